// Round 16
// baseline (570.909 us; speedup 1.0000x reference)
//
#include <hip/hip_runtime.h>
#include <hip/hip_bf16.h>
#include <stdint.h>

#define T_TOK 4096
#define H_DIM 1024
#define F_DIM 4096
#define NE 8
#define MG_BLKS 40   // ceil((2T + 8*255)/256): max 256-aligned m-chunks

typedef float    f32x4  __attribute__((ext_vector_type(4)));
typedef __bf16   bf16x8 __attribute__((ext_vector_type(8)));
typedef uint16_t u16x8  __attribute__((ext_vector_type(8)));

#define AS1 __attribute__((address_space(1)))
#define AS3 __attribute__((address_space(3)))

__device__ __forceinline__ uint16_t f2bf(float f) {
  return __builtin_bit_cast(uint16_t, __float2bfloat16(f));
}

__device__ __forceinline__ void gld16(const void* g, void* l) {
  __builtin_amdgcn_global_load_lds((const AS1 void*)g, (AS3 void*)l, 16, 0, 0);
}

// read 8 consecutive k-elements of a fp32 LDS tile (16B-chunk XOR swizzled),
// convert to bf16x8 fragment
__device__ __forceinline__ bf16x8 ldsB_frag(const float* tile, int row, int kg) {
  const int p0 = (2 * kg) ^ (row & 15);
  const int p1 = (2 * kg + 1) ^ (row & 15);
  const f32x4 v0 = *(const f32x4*)&tile[row * 64 + p0 * 4];
  const f32x4 v1 = *(const f32x4*)&tile[row * 64 + p1 * 4];
  u16x8 ub;
#pragma unroll
  for (int j = 0; j < 4; ++j) { ub[j] = f2bf(v0[j]); ub[j + 4] = f2bf(v1[j]); }
  return __builtin_bit_cast(bf16x8, ub);
}

// per-block scan of cnt -> 256-aligned bases (prefix_k folded in)
__device__ __forceinline__ void calc_base(const int* cnt, int* base9) {
  int b = 0;
#pragma unroll
  for (int e = 0; e < NE; ++e) { base9[e] = b; b += (cnt[e] + 255) & ~255; }
  base9[NE] = b;
}

// ---------------- router: logits (fp32, exact), top-2 gates, compaction, x->bf16
__global__ __launch_bounds__(256) void router_k(
    const float* __restrict__ x, const float* __restrict__ wr,
    float* __restrict__ logits, uint16_t* __restrict__ xb,
    int* __restrict__ pairTok, float* __restrict__ pairGate,
    int* __restrict__ tokSlot, int* __restrict__ cnt)
{
  const int lane = threadIdx.x & 63;
  const int wid  = threadIdx.x >> 6;
  const int t    = blockIdx.x * 4 + wid;

  const float* xp = x + (size_t)t * H_DIM + lane * 16;
  f32x4 xv[4];
#pragma unroll
  for (int i = 0; i < 4; ++i) xv[i] = *(const f32x4*)(xp + 4 * i);

  u16x8 o0, o1;
#pragma unroll
  for (int j = 0; j < 4; ++j) {
    o0[j] = f2bf(xv[0][j]); o0[j + 4] = f2bf(xv[1][j]);
    o1[j] = f2bf(xv[2][j]); o1[j + 4] = f2bf(xv[3][j]);
  }
  uint16_t* xbp = xb + (size_t)t * H_DIM + lane * 16;
  *(u16x8*)xbp       = o0;
  *(u16x8*)(xbp + 8) = o1;

  float s[NE];
#pragma unroll
  for (int e = 0; e < NE; ++e) {
    const float* wp = wr + e * H_DIM + lane * 16;
    float acc = 0.f;
#pragma unroll
    for (int i = 0; i < 4; ++i) {
      f32x4 wv = *(const f32x4*)(wp + 4 * i);
#pragma unroll
      for (int j = 0; j < 4; ++j) acc += xv[i][j] * wv[j];
    }
#pragma unroll
    for (int off = 32; off > 0; off >>= 1) acc += __shfl_xor(acc, off, 64);
    s[e] = acc;
  }

  if (lane == 0) {
#pragma unroll
    for (int e = 0; e < NE; ++e) logits[t * NE + e] = s[e];
    int e1 = 0;
#pragma unroll
    for (int e = 1; e < NE; ++e) if (s[e] > s[e1]) e1 = e;
    int e2 = (e1 == 0) ? 1 : 0;
#pragma unroll
    for (int e = 0; e < NE; ++e)
      if (e != e1 && e != e2 && s[e] > s[e2]) e2 = e;
    const float d  = s[e2] - s[e1];              // <= 0
    const float g1 = 1.f / (1.f + __expf(d));
    const float g2 = 1.f - g1;
    int i1 = atomicAdd(cnt + e1, 1);
    pairTok[e1 * T_TOK + i1] = t;  pairGate[e1 * T_TOK + i1] = g1;
    int i2 = atomicAdd(cnt + e2, 1);
    pairTok[e2 * T_TOK + i2] = t;  pairGate[e2 * T_TOK + i2] = g2;
    int4 sl; sl.x = e1; sl.y = i1; sl.z = e2; sl.w = i2;
    ((int4*)tokSlot)[t] = sl;
  }
}

// ---------------- stage 1: h = gate * silu(x@w1^T) * (x@w3^T)
// R13-exact (best measured: ~235 us): BM=256 x BN=64, BK=64, 4 waves,
// gld16 A bf16 + B raw fp32, cvt at fragment read. Dense 2-D grid.
__global__ __launch_bounds__(256, 2) void ffn1_k(
    const uint16_t* __restrict__ xb, const float* __restrict__ w1,
    const float* __restrict__ w3, uint16_t* __restrict__ hbuf,
    const int* __restrict__ pairTok, const float* __restrict__ pairGate,
    const int* __restrict__ cnt)
{
  int base[NE + 1];
  calc_base(cnt, base);
  const int mg0 = blockIdx.y * 256;
  if (mg0 >= base[NE]) return;
  int e = 0;
#pragma unroll
  for (int k = 1; k < NE; ++k) if (mg0 >= base[k]) e = k;
  const int m0   = mg0 - base[e];
  const int cnte = cnt[e];
  const int n0   = blockIdx.x * 64;
  const int tid  = threadIdx.x;
  const int lane = tid & 63;
  const int wid  = tid >> 6;
  const int wm   = (wid >> 1) * 128;   // 0 or 128
  const int wn   = (wid & 1) * 32;     // 0 or 32

  __shared__ __align__(16) uint16_t lsA [256 * 64];  // 32 KB bf16
  __shared__ __align__(16) float    lsB1[ 64 * 64];  // 16 KB fp32
  __shared__ __align__(16) float    lsB3[ 64 * 64];  // 16 KB fp32

  const float* w1e = w1 + (size_t)e * F_DIM * H_DIM;
  const float* w3e = w3 + (size_t)e * F_DIM * H_DIM;

  const uint16_t* asrc[8];
#pragma unroll
  for (int q = 0; q < 8; ++q) {
    const int c = q * 256 + tid;
    const int row = c >> 3, pos = c & 7;
    const int kc  = pos ^ (row & 7);
    int ar = m0 + row; if (ar >= cnte) ar = cnte - 1;
    const int tok = pairTok[e * T_TOK + ar];
    asrc[q] = xb + (size_t)tok * H_DIM + kc * 8;
  }
  const float* b1src[4];
  const float* b3src[4];
#pragma unroll
  for (int q = 0; q < 4; ++q) {
    const int c = q * 256 + tid;
    const int row = c >> 4, pos = c & 15;
    const int kc  = pos ^ (row & 15);
    b1src[q] = w1e + (size_t)(n0 + row) * H_DIM + kc * 4;
    b3src[q] = w3e + (size_t)(n0 + row) * H_DIM + kc * 4;
  }

  const f32x4 fz = {0.f, 0.f, 0.f, 0.f};
  f32x4 acc1[8][2], acc3[8][2];
#pragma unroll
  for (int i = 0; i < 8; ++i)
#pragma unroll
    for (int j = 0; j < 2; ++j) { acc1[i][j] = fz; acc3[i][j] = fz; }

  for (int kt = 0; kt < H_DIM; kt += 64) {
    __syncthreads();
#pragma unroll
    for (int q = 0; q < 8; ++q)
      gld16(asrc[q] + kt, &lsA[(q * 256 + tid) * 8]);
#pragma unroll
    for (int q = 0; q < 4; ++q) {
      gld16(b1src[q] + kt, &lsB1[(q * 256 + tid) * 4]);
      gld16(b3src[q] + kt, &lsB3[(q * 256 + tid) * 4]);
    }
    __syncthreads();
#pragma unroll
    for (int ks = 0; ks < 2; ++ks) {
      const int kg = ks * 4 + (lane >> 4);
      bf16x8 af[8], b1f[2], b3f[2];
#pragma unroll
      for (int i = 0; i < 8; ++i) {
        const int ar = wm + i * 16 + (lane & 15);
        af[i] = *(const bf16x8*)&lsA[ar * 64 + ((kg ^ (ar & 7)) * 8)];
      }
#pragma unroll
      for (int j = 0; j < 2; ++j) {
        const int br = wn + j * 16 + (lane & 15);
        b1f[j] = ldsB_frag(lsB1, br, kg);
        b3f[j] = ldsB_frag(lsB3, br, kg);
      }
#pragma unroll
      for (int i = 0; i < 8; ++i)
#pragma unroll
        for (int j = 0; j < 2; ++j) {
          acc1[i][j] = __builtin_amdgcn_mfma_f32_16x16x32_bf16(af[i], b1f[j], acc1[i][j], 0, 0, 0);
          acc3[i][j] = __builtin_amdgcn_mfma_f32_16x16x32_bf16(af[i], b3f[j], acc3[i][j], 0, 0, 0);
        }
    }
  }

  // epilogue: h = g * silu(a1) * a3 -> bf16. C/D: col=lane&15, row=(lane>>4)*4+r
  const int be = base[e];
#pragma unroll
  for (int i = 0; i < 8; ++i) {
#pragma unroll
    for (int rr = 0; rr < 4; ++rr) {
      const int lrow = m0 + wm + i * 16 + (lane >> 4) * 4 + rr;
      if (lrow < cnte) {
        const float g = pairGate[e * T_TOK + lrow];
        uint16_t* hp = hbuf + (size_t)(be + lrow) * F_DIM + n0 + wn + (lane & 15);
#pragma unroll
        for (int j = 0; j < 2; ++j) {
          const float a  = acc1[i][j][rr];
          const float hv = g * (a / (1.f + __expf(-a))) * acc3[i][j][rr];
          hp[j * 16] = f2bf(hv);
        }
      }
    }
  }
}

// ---------------- stage 2 (PIPELINED): y[row] = h[row] @ w2^T
// R13-exact inner loop (BM=256 x BN=128, 4 waves, acc[8][4], B raw fp32).
// NEW: full A+B double-buffer (128 KB LDS — free: grid is ~1 block/CU) with
// counted vmcnt(16): tile t+1's 16 loads stay in flight across barriers,
// no drain in the main loop. Grid-starved kernel -> intra-block pipelining
// is the only available latency cover.
__global__ __launch_bounds__(256, 1) void ffn2_k(
    const uint16_t* __restrict__ hbuf, const float* __restrict__ w2,
    uint16_t* __restrict__ y, const int* __restrict__ cnt)
{
  int base[NE + 1];
  calc_base(cnt, base);
  const int mg0 = blockIdx.y * 256;
  if (mg0 >= base[NE]) return;
  int e = 0;
#pragma unroll
  for (int k = 1; k < NE; ++k) if (mg0 >= base[k]) e = k;
  const int m0   = mg0 - base[e];
  const int cnte = cnt[e];
  const int n0   = blockIdx.x * 128;
  const int tid  = threadIdx.x;
  const int lane = tid & 63;
  const int wid  = tid >> 6;
  const int wm   = (wid >> 1) * 128;   // 0 or 128
  const int wn   = (wid & 1) * 64;     // 0 or 64

  __shared__ __align__(16) uint16_t lsA[2][256 * 64];   // 64 KB bf16
  __shared__ __align__(16) float    lsB[2][128 * 64];   // 64 KB fp32

  const int be = base[e];
  const float* w2e = w2 + (size_t)e * H_DIM * F_DIM;

  const uint16_t* asrc[8];
#pragma unroll
  for (int q = 0; q < 8; ++q) {
    const int c = q * 256 + tid;
    const int row = c >> 3, pos = c & 7;
    const int kc  = pos ^ (row & 7);
    int rr = m0 + row; if (rr >= cnte) rr = cnte - 1;
    asrc[q] = hbuf + (size_t)(be + rr) * F_DIM + kc * 8;
  }
  const float* bsrc[8];
#pragma unroll
  for (int q = 0; q < 8; ++q) {
    const int c = q * 256 + tid;
    const int row = c >> 4, pos = c & 15;
    const int kc  = pos ^ (row & 15);
    bsrc[q] = w2e + (size_t)(n0 + row) * F_DIM + kc * 4;
  }

#define STAGE2(buf, koff)                                                 \
  {                                                                       \
    _Pragma("unroll") for (int q = 0; q < 8; ++q)                         \
      gld16(asrc[q] + (koff), &lsA[buf][(q * 256 + tid) * 8]);            \
    _Pragma("unroll") for (int q = 0; q < 8; ++q)                         \
      gld16(bsrc[q] + (koff), &lsB[buf][(q * 256 + tid) * 4]);            \
  }

#define COMPUTE2(cur)                                                     \
  {                                                                       \
    _Pragma("unroll") for (int ks = 0; ks < 2; ++ks) {                    \
      const int kg = ks * 4 + (lane >> 4);                                \
      bf16x8 af[8], bf[4];                                                \
      _Pragma("unroll") for (int i = 0; i < 8; ++i) {                     \
        const int ar = wm + i * 16 + (lane & 15);                         \
        af[i] = *(const bf16x8*)&lsA[cur][ar * 64 + ((kg ^ (ar & 7)) * 8)]; \
      }                                                                   \
      _Pragma("unroll") for (int j = 0; j < 4; ++j) {                     \
        const int br = wn + j * 16 + (lane & 15);                         \
        bf[j] = ldsB_frag(lsB[cur], br, kg);                              \
      }                                                                   \
      _Pragma("unroll") for (int i = 0; i < 8; ++i)                       \
        _Pragma("unroll") for (int j = 0; j < 4; ++j)                     \
          acc[i][j] = __builtin_amdgcn_mfma_f32_16x16x32_bf16(af[i], bf[j], acc[i][j], 0, 0, 0); \
    }                                                                     \
  }

  const f32x4 fz = {0.f, 0.f, 0.f, 0.f};
  f32x4 acc[8][4];
#pragma unroll
  for (int i = 0; i < 8; ++i)
#pragma unroll
    for (int j = 0; j < 4; ++j) acc[i][j] = fz;

  const int NT = F_DIM / 64;   // 64 K-tiles
  // prologue: tiles 0 and 1 in flight (16 loads each per thread)
  STAGE2(0, 0)
  STAGE2(1, 64)

  for (int t = 0; t < NT - 1; ++t) {
    const int cur = t & 1;
    asm volatile("s_waitcnt vmcnt(16)" ::: "memory");  // tile t landed; t+1 flying
    __builtin_amdgcn_s_barrier();                      // all waves see tile t
    __builtin_amdgcn_s_setprio(1);
    COMPUTE2(cur)
    __builtin_amdgcn_s_setprio(0);
    __builtin_amdgcn_s_barrier();                      // all waves done with buf[cur]
    if (t + 2 < NT) STAGE2(cur, (t + 2) * 64)          // refill freed buffer
  }
  {
    asm volatile("s_waitcnt vmcnt(0)" ::: "memory");   // final tile
    __builtin_amdgcn_s_barrier();
    COMPUTE2((NT - 1) & 1)
  }
#undef STAGE2
#undef COMPUTE2

  // epilogue: plain bf16 stores into pair-row buffer (gate already in h)
#pragma unroll
  for (int i = 0; i < 8; ++i) {
#pragma unroll
    for (int rr = 0; rr < 4; ++rr) {
      const int lrow = m0 + wm + i * 16 + (lane >> 4) * 4 + rr;
      if (lrow < cnte) {
        uint16_t* yp = y + (size_t)(be + lrow) * H_DIM + n0 + wn + (lane & 15);
#pragma unroll
        for (int j = 0; j < 4; ++j)
          yp[j * 16] = f2bf(acc[i][j][rr]);
      }
    }
  }
}

// ---------------- combine: out[t] = y[slot1(t)] + y[slot2(t)]  (fp32 out)
__global__ __launch_bounds__(256) void combine_k(
    const uint16_t* __restrict__ y, const int* __restrict__ tokSlot,
    const int* __restrict__ cnt, float* __restrict__ out)
{
  int base[NE + 1];
  calc_base(cnt, base);
  const int t = blockIdx.x * 2 + (threadIdx.x >> 7);
  const int c = (threadIdx.x & 127) * 8;
  const int4 s = ((const int4*)tokSlot)[t];
  const uint16_t* y1 = y + (size_t)(base[s.x] + s.y) * H_DIM + c;
  const uint16_t* y2 = y + (size_t)(base[s.z] + s.w) * H_DIM + c;
  const u16x8 a = *(const u16x8*)y1;
  const u16x8 b = *(const u16x8*)y2;
  float* op = out + (size_t)t * H_DIM + c;
  f32x4 o0, o1;
#pragma unroll
  for (int j = 0; j < 4; ++j) {
    o0[j] = __bfloat162float(__hip_bfloat16_raw{a[j]}) +
            __bfloat162float(__hip_bfloat16_raw{b[j]});
    o1[j] = __bfloat162float(__hip_bfloat16_raw{a[j + 4]}) +
            __bfloat162float(__hip_bfloat16_raw{b[j + 4]});
  }
  *(f32x4*)op       = o0;
  *(f32x4*)(op + 4) = o1;
}

extern "C" void kernel_launch(void* const* d_in, const int* in_sizes, int n_in,
                              void* d_out, int out_size, void* d_ws, size_t ws_size,
                              hipStream_t stream)
{
  const float* x  = (const float*)d_in[0];
  const float* wr = (const float*)d_in[1];
  const float* w1 = (const float*)d_in[2];
  const float* w2 = (const float*)d_in[3];
  const float* w3 = (const float*)d_in[4];
  float* out    = (float*)d_out;
  float* logits = out + (size_t)T_TOK * H_DIM;

  uint8_t* ws = (uint8_t*)d_ws;
  const size_t PADROWS  = (size_t)MG_BLKS * 256;                    // 10240
  const size_t XB_OFF   = 0;
  const size_t HB_OFF   = XB_OFF + (size_t)T_TOK * H_DIM * 2;       // 8 MB
  const size_t Y_OFF    = HB_OFF + PADROWS * F_DIM * 2;             // +80 MB
  const size_t PT_OFF   = Y_OFF + PADROWS * H_DIM * 2;              // +20 MB
  const size_t PG_OFF   = PT_OFF + (size_t)NE * T_TOK * 4;
  const size_t TS_OFF   = PG_OFF + (size_t)NE * T_TOK * 4;
  const size_t CNT_OFF  = TS_OFF + (size_t)T_TOK * 16;
  const size_t NEED     = CNT_OFF + 64;
  if (ws_size < NEED) return;

  uint16_t* xb      = (uint16_t*)(ws + XB_OFF);
  uint16_t* hb      = (uint16_t*)(ws + HB_OFF);
  uint16_t* yb      = (uint16_t*)(ws + Y_OFF);
  int*      pairTok = (int*)(ws + PT_OFF);
  float*    pairGate= (float*)(ws + PG_OFF);
  int*      tokSlot = (int*)(ws + TS_OFF);
  int*      cnt     = (int*)(ws + CNT_OFF);

  hipMemsetAsync(cnt, 0, 64, stream);
  router_k<<<T_TOK / 4, 256, 0, stream>>>(x, wr, logits, xb, pairTok, pairGate, tokSlot, cnt);
  ffn1_k<<<dim3(F_DIM / 64, MG_BLKS, 1), 256, 0, stream>>>(xb, w1, w3, hb, pairTok, pairGate, cnt);
  ffn2_k<<<dim3(H_DIM / 128, MG_BLKS, 1), 256, 0, stream>>>(hb, w2, yb, cnt);
  combine_k<<<T_TOK / 2, 256, 0, stream>>>(yb, tokSlot, cnt, out);
}

// Round 17
// 472.125 us; speedup vs baseline: 1.2092x; 1.2092x over previous
//
#include <hip/hip_runtime.h>
#include <hip/hip_bf16.h>
#include <stdint.h>

#define T_TOK 4096
#define H_DIM 1024
#define F_DIM 4096
#define NE 8
#define MG_BLKS 40   // ceil((2T + 8*255)/256): max 256-aligned m-chunks
#define PADROWS (MG_BLKS * 256)

typedef float    f32x4  __attribute__((ext_vector_type(4)));
typedef __bf16   bf16x8 __attribute__((ext_vector_type(8)));
typedef uint16_t u16x8  __attribute__((ext_vector_type(8)));

#define AS1 __attribute__((address_space(1)))
#define AS3 __attribute__((address_space(3)))

__device__ __forceinline__ uint16_t f2bf(float f) {
  return __builtin_bit_cast(uint16_t, __float2bfloat16(f));
}

__device__ __forceinline__ float bf2f(uint16_t u) {
  return __bfloat162float(__hip_bfloat16_raw{u});
}

__device__ __forceinline__ void gld16(const void* g, void* l) {
  __builtin_amdgcn_global_load_lds((const AS1 void*)g, (AS3 void*)l, 16, 0, 0);
}

// read 8 consecutive k-elements of a fp32 LDS tile (16B-chunk XOR swizzled),
// convert to bf16x8 fragment
__device__ __forceinline__ bf16x8 ldsB_frag(const float* tile, int row, int kg) {
  const int p0 = (2 * kg) ^ (row & 15);
  const int p1 = (2 * kg + 1) ^ (row & 15);
  const f32x4 v0 = *(const f32x4*)&tile[row * 64 + p0 * 4];
  const f32x4 v1 = *(const f32x4*)&tile[row * 64 + p1 * 4];
  u16x8 ub;
#pragma unroll
  for (int j = 0; j < 4; ++j) { ub[j] = f2bf(v0[j]); ub[j + 4] = f2bf(v1[j]); }
  return __builtin_bit_cast(bf16x8, ub);
}

// per-block scan of cnt -> 256-aligned bases (prefix_k folded in)
__device__ __forceinline__ void calc_base(const int* cnt, int* base9) {
  int b = 0;
#pragma unroll
  for (int e = 0; e < NE; ++e) { base9[e] = b; b += (cnt[e] + 255) & ~255; }
  base9[NE] = b;
}

// ---------------- router: logits (fp32, exact), top-2 gates, compaction, x->bf16
__global__ __launch_bounds__(256) void router_k(
    const float* __restrict__ x, const float* __restrict__ wr,
    float* __restrict__ logits, uint16_t* __restrict__ xb,
    int* __restrict__ pairTok, float* __restrict__ pairGate,
    int* __restrict__ tokSlot, int* __restrict__ cnt)
{
  const int lane = threadIdx.x & 63;
  const int wid  = threadIdx.x >> 6;
  const int t    = blockIdx.x * 4 + wid;

  const float* xp = x + (size_t)t * H_DIM + lane * 16;
  f32x4 xv[4];
#pragma unroll
  for (int i = 0; i < 4; ++i) xv[i] = *(const f32x4*)(xp + 4 * i);

  u16x8 o0, o1;
#pragma unroll
  for (int j = 0; j < 4; ++j) {
    o0[j] = f2bf(xv[0][j]); o0[j + 4] = f2bf(xv[1][j]);
    o1[j] = f2bf(xv[2][j]); o1[j + 4] = f2bf(xv[3][j]);
  }
  uint16_t* xbp = xb + (size_t)t * H_DIM + lane * 16;
  *(u16x8*)xbp       = o0;
  *(u16x8*)(xbp + 8) = o1;

  float s[NE];
#pragma unroll
  for (int e = 0; e < NE; ++e) {
    const float* wp = wr + e * H_DIM + lane * 16;
    float acc = 0.f;
#pragma unroll
    for (int i = 0; i < 4; ++i) {
      f32x4 wv = *(const f32x4*)(wp + 4 * i);
#pragma unroll
      for (int j = 0; j < 4; ++j) acc += xv[i][j] * wv[j];
    }
#pragma unroll
    for (int off = 32; off > 0; off >>= 1) acc += __shfl_xor(acc, off, 64);
    s[e] = acc;
  }

  if (lane == 0) {
#pragma unroll
    for (int e = 0; e < NE; ++e) logits[t * NE + e] = s[e];
    int e1 = 0;
#pragma unroll
    for (int e = 1; e < NE; ++e) if (s[e] > s[e1]) e1 = e;
    int e2 = (e1 == 0) ? 1 : 0;
#pragma unroll
    for (int e = 0; e < NE; ++e)
      if (e != e1 && e != e2 && s[e] > s[e2]) e2 = e;
    const float d  = s[e2] - s[e1];              // <= 0
    const float g1 = 1.f / (1.f + __expf(d));
    const float g2 = 1.f - g1;
    int i1 = atomicAdd(cnt + e1, 1);
    pairTok[e1 * T_TOK + i1] = t;  pairGate[e1 * T_TOK + i1] = g1;
    int i2 = atomicAdd(cnt + e2, 1);
    pairTok[e2 * T_TOK + i2] = t;  pairGate[e2 * T_TOK + i2] = g2;
    int4 sl; sl.x = e1; sl.y = i1; sl.z = e2; sl.w = i2;
    ((int4*)tokSlot)[t] = sl;
  }
}

// ---------------- stage 1: h = gate * silu(x@w1^T) * (x@w3^T)
// R13-exact (best measured: ~235 us): BM=256 x BN=64, BK=64, 4 waves,
// gld16 A bf16 + B raw fp32, cvt at fragment read. Dense 2-D grid.
__global__ __launch_bounds__(256, 2) void ffn1_k(
    const uint16_t* __restrict__ xb, const float* __restrict__ w1,
    const float* __restrict__ w3, uint16_t* __restrict__ hbuf,
    const int* __restrict__ pairTok, const float* __restrict__ pairGate,
    const int* __restrict__ cnt)
{
  int base[NE + 1];
  calc_base(cnt, base);
  const int mg0 = blockIdx.y * 256;
  if (mg0 >= base[NE]) return;
  int e = 0;
#pragma unroll
  for (int k = 1; k < NE; ++k) if (mg0 >= base[k]) e = k;
  const int m0   = mg0 - base[e];
  const int cnte = cnt[e];
  const int n0   = blockIdx.x * 64;
  const int tid  = threadIdx.x;
  const int lane = tid & 63;
  const int wid  = tid >> 6;
  const int wm   = (wid >> 1) * 128;   // 0 or 128
  const int wn   = (wid & 1) * 32;     // 0 or 32

  __shared__ __align__(16) uint16_t lsA [256 * 64];  // 32 KB bf16
  __shared__ __align__(16) float    lsB1[ 64 * 64];  // 16 KB fp32
  __shared__ __align__(16) float    lsB3[ 64 * 64];  // 16 KB fp32

  const float* w1e = w1 + (size_t)e * F_DIM * H_DIM;
  const float* w3e = w3 + (size_t)e * F_DIM * H_DIM;

  const uint16_t* asrc[8];
#pragma unroll
  for (int q = 0; q < 8; ++q) {
    const int c = q * 256 + tid;
    const int row = c >> 3, pos = c & 7;
    const int kc  = pos ^ (row & 7);
    int ar = m0 + row; if (ar >= cnte) ar = cnte - 1;
    const int tok = pairTok[e * T_TOK + ar];
    asrc[q] = xb + (size_t)tok * H_DIM + kc * 8;
  }
  const float* b1src[4];
  const float* b3src[4];
#pragma unroll
  for (int q = 0; q < 4; ++q) {
    const int c = q * 256 + tid;
    const int row = c >> 4, pos = c & 15;
    const int kc  = pos ^ (row & 15);
    b1src[q] = w1e + (size_t)(n0 + row) * H_DIM + kc * 4;
    b3src[q] = w3e + (size_t)(n0 + row) * H_DIM + kc * 4;
  }

  const f32x4 fz = {0.f, 0.f, 0.f, 0.f};
  f32x4 acc1[8][2], acc3[8][2];
#pragma unroll
  for (int i = 0; i < 8; ++i)
#pragma unroll
    for (int j = 0; j < 2; ++j) { acc1[i][j] = fz; acc3[i][j] = fz; }

  for (int kt = 0; kt < H_DIM; kt += 64) {
    __syncthreads();
#pragma unroll
    for (int q = 0; q < 8; ++q)
      gld16(asrc[q] + kt, &lsA[(q * 256 + tid) * 8]);
#pragma unroll
    for (int q = 0; q < 4; ++q) {
      gld16(b1src[q] + kt, &lsB1[(q * 256 + tid) * 4]);
      gld16(b3src[q] + kt, &lsB3[(q * 256 + tid) * 4]);
    }
    __syncthreads();
#pragma unroll
    for (int ks = 0; ks < 2; ++ks) {
      const int kg = ks * 4 + (lane >> 4);
      bf16x8 af[8], b1f[2], b3f[2];
#pragma unroll
      for (int i = 0; i < 8; ++i) {
        const int ar = wm + i * 16 + (lane & 15);
        af[i] = *(const bf16x8*)&lsA[ar * 64 + ((kg ^ (ar & 7)) * 8)];
      }
#pragma unroll
      for (int j = 0; j < 2; ++j) {
        const int br = wn + j * 16 + (lane & 15);
        b1f[j] = ldsB_frag(lsB1, br, kg);
        b3f[j] = ldsB_frag(lsB3, br, kg);
      }
#pragma unroll
      for (int i = 0; i < 8; ++i)
#pragma unroll
        for (int j = 0; j < 2; ++j) {
          acc1[i][j] = __builtin_amdgcn_mfma_f32_16x16x32_bf16(af[i], b1f[j], acc1[i][j], 0, 0, 0);
          acc3[i][j] = __builtin_amdgcn_mfma_f32_16x16x32_bf16(af[i], b3f[j], acc3[i][j], 0, 0, 0);
        }
    }
  }

  // epilogue: h = g * silu(a1) * a3 -> bf16. C/D: col=lane&15, row=(lane>>4)*4+r
  const int be = base[e];
#pragma unroll
  for (int i = 0; i < 8; ++i) {
#pragma unroll
    for (int rr = 0; rr < 4; ++rr) {
      const int lrow = m0 + wm + i * 16 + (lane >> 4) * 4 + rr;
      if (lrow < cnte) {
        const float g = pairGate[e * T_TOK + lrow];
        uint16_t* hp = hbuf + (size_t)(be + lrow) * F_DIM + n0 + wn + (lane & 15);
#pragma unroll
        for (int j = 0; j < 2; ++j) {
          const float a  = acc1[i][j][rr];
          const float hv = g * (a / (1.f + __expf(-a))) * acc3[i][j][rr];
          hp[j * 16] = f2bf(hv);
        }
      }
    }
  }
}

// ---------------- stage 2: y[kz][row] = h[row, kz-half] @ w2^T  (SPLIT-K=2)
// R13-exact inner loop (BM=256 x BN=128, 4 waves, acc[8][4], B raw fp32 via
// gld16, 64 KB LDS, 2 blocks/CU). grid.z = K-half -> partials go to separate
// y buffers (NO atomics, no occupancy change); grid 272 -> 544 blocks.
__global__ __launch_bounds__(256, 2) void ffn2_k(
    const uint16_t* __restrict__ hbuf, const float* __restrict__ w2,
    uint16_t* __restrict__ y, const int* __restrict__ cnt)
{
  int base[NE + 1];
  calc_base(cnt, base);
  const int mg0 = blockIdx.y * 256;
  if (mg0 >= base[NE]) return;
  int e = 0;
#pragma unroll
  for (int k = 1; k < NE; ++k) if (mg0 >= base[k]) e = k;
  const int m0   = mg0 - base[e];
  const int cnte = cnt[e];
  const int n0   = blockIdx.x * 128;
  const int k0   = blockIdx.z * (F_DIM / 2);
  const int tid  = threadIdx.x;
  const int lane = tid & 63;
  const int wid  = tid >> 6;
  const int wm   = (wid >> 1) * 128;   // 0 or 128
  const int wn   = (wid & 1) * 64;     // 0 or 64

  __shared__ __align__(16) uint16_t lsA[256 * 64];   // 32 KB bf16
  __shared__ __align__(16) float    lsB[128 * 64];   // 32 KB fp32

  const int be = base[e];
  const float* w2e = w2 + (size_t)e * H_DIM * F_DIM;
  uint16_t* ybuf = y + (size_t)blockIdx.z * PADROWS * H_DIM;

  const uint16_t* asrc[8];
#pragma unroll
  for (int q = 0; q < 8; ++q) {
    const int c = q * 256 + tid;
    const int row = c >> 3, pos = c & 7;
    const int kc  = pos ^ (row & 7);
    int rr = m0 + row; if (rr >= cnte) rr = cnte - 1;
    asrc[q] = hbuf + (size_t)(be + rr) * F_DIM + k0 + kc * 8;
  }
  const float* bsrc[8];
#pragma unroll
  for (int q = 0; q < 8; ++q) {
    const int c = q * 256 + tid;
    const int row = c >> 4, pos = c & 15;
    const int kc  = pos ^ (row & 15);
    bsrc[q] = w2e + (size_t)(n0 + row) * F_DIM + k0 + kc * 4;
  }

  const f32x4 fz = {0.f, 0.f, 0.f, 0.f};
  f32x4 acc[8][4];
#pragma unroll
  for (int i = 0; i < 8; ++i)
#pragma unroll
    for (int j = 0; j < 4; ++j) acc[i][j] = fz;

  for (int kt = 0; kt < F_DIM / 2; kt += 64) {
    __syncthreads();
#pragma unroll
    for (int q = 0; q < 8; ++q)
      gld16(asrc[q] + kt, &lsA[(q * 256 + tid) * 8]);
#pragma unroll
    for (int q = 0; q < 8; ++q)
      gld16(bsrc[q] + kt, &lsB[(q * 256 + tid) * 4]);
    __syncthreads();
#pragma unroll
    for (int ks = 0; ks < 2; ++ks) {
      const int kg = ks * 4 + (lane >> 4);
      bf16x8 af[8], bf[4];
#pragma unroll
      for (int i = 0; i < 8; ++i) {
        const int ar = wm + i * 16 + (lane & 15);
        af[i] = *(const bf16x8*)&lsA[ar * 64 + ((kg ^ (ar & 7)) * 8)];
      }
#pragma unroll
      for (int j = 0; j < 4; ++j) {
        const int br = wn + j * 16 + (lane & 15);
        bf[j] = ldsB_frag(lsB, br, kg);
      }
#pragma unroll
      for (int i = 0; i < 8; ++i)
#pragma unroll
        for (int j = 0; j < 4; ++j)
          acc[i][j] = __builtin_amdgcn_mfma_f32_16x16x32_bf16(af[i], bf[j], acc[i][j], 0, 0, 0);
    }
  }

  // epilogue: bf16 partial stores into this K-half's y buffer (no atomics)
#pragma unroll
  for (int i = 0; i < 8; ++i) {
#pragma unroll
    for (int rr = 0; rr < 4; ++rr) {
      const int lrow = m0 + wm + i * 16 + (lane >> 4) * 4 + rr;
      if (lrow < cnte) {
        uint16_t* yp = ybuf + (size_t)(be + lrow) * H_DIM + n0 + wn + (lane & 15);
#pragma unroll
        for (int j = 0; j < 4; ++j)
          yp[j * 16] = f2bf(acc[i][j][rr]);
      }
    }
  }
}

// ---------------- combine: out[t] = sum over {slot1,slot2} x {khalf0,khalf1}
__global__ __launch_bounds__(256) void combine_k(
    const uint16_t* __restrict__ y, const int* __restrict__ tokSlot,
    const int* __restrict__ cnt, float* __restrict__ out)
{
  int base[NE + 1];
  calc_base(cnt, base);
  const int t = blockIdx.x * 2 + (threadIdx.x >> 7);
  const int c = (threadIdx.x & 127) * 8;
  const int4 s = ((const int4*)tokSlot)[t];
  const size_t r1 = (size_t)(base[s.x] + s.y) * H_DIM + c;
  const size_t r2 = (size_t)(base[s.z] + s.w) * H_DIM + c;
  const size_t HSTRIDE = (size_t)PADROWS * H_DIM;
  const u16x8 a0 = *(const u16x8*)(y + r1);
  const u16x8 a1 = *(const u16x8*)(y + HSTRIDE + r1);
  const u16x8 b0 = *(const u16x8*)(y + r2);
  const u16x8 b1 = *(const u16x8*)(y + HSTRIDE + r2);
  float* op = out + (size_t)t * H_DIM + c;
  f32x4 o0, o1;
#pragma unroll
  for (int j = 0; j < 4; ++j) {
    o0[j] = bf2f(a0[j])     + bf2f(a1[j])     + bf2f(b0[j])     + bf2f(b1[j]);
    o1[j] = bf2f(a0[j + 4]) + bf2f(a1[j + 4]) + bf2f(b0[j + 4]) + bf2f(b1[j + 4]);
  }
  *(f32x4*)op       = o0;
  *(f32x4*)(op + 4) = o1;
}

extern "C" void kernel_launch(void* const* d_in, const int* in_sizes, int n_in,
                              void* d_out, int out_size, void* d_ws, size_t ws_size,
                              hipStream_t stream)
{
  const float* x  = (const float*)d_in[0];
  const float* wr = (const float*)d_in[1];
  const float* w1 = (const float*)d_in[2];
  const float* w2 = (const float*)d_in[3];
  const float* w3 = (const float*)d_in[4];
  float* out    = (float*)d_out;
  float* logits = out + (size_t)T_TOK * H_DIM;

  uint8_t* ws = (uint8_t*)d_ws;
  const size_t XB_OFF   = 0;
  const size_t HB_OFF   = XB_OFF + (size_t)T_TOK * H_DIM * 2;       // 8 MB
  const size_t Y_OFF    = HB_OFF + (size_t)PADROWS * F_DIM * 2;     // +80 MB
  const size_t PT_OFF   = Y_OFF + (size_t)2 * PADROWS * H_DIM * 2;  // +40 MB (2 K-halves)
  const size_t PG_OFF   = PT_OFF + (size_t)NE * T_TOK * 4;
  const size_t TS_OFF   = PG_OFF + (size_t)NE * T_TOK * 4;
  const size_t CNT_OFF  = TS_OFF + (size_t)T_TOK * 16;
  const size_t NEED     = CNT_OFF + 64;
  if (ws_size < NEED) return;

  uint16_t* xb      = (uint16_t*)(ws + XB_OFF);
  uint16_t* hb      = (uint16_t*)(ws + HB_OFF);
  uint16_t* yb      = (uint16_t*)(ws + Y_OFF);
  int*      pairTok = (int*)(ws + PT_OFF);
  float*    pairGate= (float*)(ws + PG_OFF);
  int*      tokSlot = (int*)(ws + TS_OFF);
  int*      cnt     = (int*)(ws + CNT_OFF);

  hipMemsetAsync(cnt, 0, 64, stream);
  router_k<<<T_TOK / 4, 256, 0, stream>>>(x, wr, logits, xb, pairTok, pairGate, tokSlot, cnt);
  ffn1_k<<<dim3(F_DIM / 64, MG_BLKS, 1), 256, 0, stream>>>(xb, w1, w3, hb, pairTok, pairGate, cnt);
  ffn2_k<<<dim3(H_DIM / 128, MG_BLKS, 2), 256, 0, stream>>>(hb, w2, yb, cnt);
  combine_k<<<T_TOK / 2, 256, 0, stream>>>(yb, tokSlot, cnt, out);
}